// Round 7
// baseline (189.058 us; speedup 1.0000x reference)
//
#include <hip/hip_runtime.h>

// SFM recurrent model via MFMA: B=2048, T=60, D=6, H=64, F=10, O=1.
//
// R12 BEST (73.7us): transposed GEMM (A=U^T static), NB=8, 256x512,
//   2 barriers/step. Latency-bound: MfmaUtil 13, VALU 36, Occ 20.
// R13/R14: multi-block axis dead. R14: halving P threads -> no change
//   => P phase NOT issue-bound (hides under latency).
// R15 (82us): M-phase shfl folds regress ~30cy each; P LDS diet neutral.
// R16 (93us)/R17 (87.6us): MFMA duplication adds ~1:1 to wall even
//   when overlapped with P -- matrix-pipe ISSUE is on the wall.
// R18 (76us): phasor + fb-vec + x-prefetch neutral; chain-split adds
//   M-path VALU -> reverted here. CONFIRMED: P-side op counts free.
// R19: cut & rebalance post-barrier MFMA issue, zero duplication:
//   (a) x-chunk MFMAs (2 of 6 per tile, h-independent) PRE-ISSUED at
//       end of P(s) for s+1 into accPre regs (asm-pinned pre-barrier).
//       Matrix pipe is idle during P -> free issue. Post-barrier
//       gate chains start from accPre: 4 MFMAs/tile.
//   (b) fre tile split by k-chunk: wave5 = B0-chunk, wave6 = B1-chunk,
//       wave7 = x-chunk (pre-issued). Raw partials -> fbp[3][16][16];
//       hi/lo fold + chunk sum moved to P (headroom proven). No shfl
//       on M path; wave-7 laggard gone.
//   Worst-SIMD post-barrier MFMA issue: 30x16=480cy -> 18x16=288cy.
//   Total MFMA count unchanged (102/block/step).
//
// Layouts (guide-verified): A[m=lane&15][k=quad*8+j]; B[k=quad*8+j]
// [n=lane&15]; C col=lane&15 (n), row=quad*4+reg (m=hcol-in-tile).
// B cols 0-7 = h_hi(b0..7), 8-15 = h_lo(b0..7).

#define BB 2048
#define TT 60
#define DD 6
#define HH 64
#define FF 10
#define NB 8      // batches per block

#define XS 968    // xsp per-batch stride in shorts (60*16 + 8 pad)
#define HSK 72    // hsp2 row stride in shorts (16 rows: 0-7 hi(b), 8-15 lo(b))
#define ZC 68     // zt hcol stride in floats (pad 64->68: banks spread)

typedef short bf16x8 __attribute__((ext_vector_type(8)));
typedef float f32x4  __attribute__((ext_vector_type(4)));
typedef float f32x2  __attribute__((ext_vector_type(2)));

__device__ __forceinline__ unsigned short f2bf(float f) {
    union { float f; unsigned u; } v; v.f = f;
    unsigned r = v.u + 0x7fffu + ((v.u >> 16) & 1u);   // RNE
    return (unsigned short)(r >> 16);
}
__device__ __forceinline__ float bf2f(unsigned short b) {
    union { unsigned u; float f; } v; v.u = ((unsigned)b) << 16; return v.f;
}
__device__ __forceinline__ float hsig_f(float v) {
    return __builtin_amdgcn_fmed3f(fmaf(v, 0.16666666666666666f, 0.5f), 0.0f, 1.0f);
}
__device__ __forceinline__ float tanh_f(float x) {
    float xc = fminf(fmaxf(x, -12.0f), 12.0f);
    float e  = __builtin_amdgcn_exp2f(xc * 2.8853900817779268f); // 2*log2(e)
    return (e - 1.0f) * __builtin_amdgcn_rcpf(e + 1.0f);
}
__device__ __forceinline__ float uni(float v) {
    return __int_as_float(__builtin_amdgcn_readfirstlane(__float_as_int(v)));
}
__device__ __forceinline__ void pinv(bf16x8& v)  { asm volatile("" : "+v"(v)); }
__device__ __forceinline__ void pinvf(f32x4& v)  { asm volatile("" : "+v"(v)); }

__global__ __launch_bounds__(512, 1)
void sfm_kernel(
    const float* __restrict__ x,
    const float* __restrict__ W_i,  const float* __restrict__ U_i,  const float* __restrict__ b_i,
    const float* __restrict__ W_ste,const float* __restrict__ U_ste,const float* __restrict__ b_ste,
    const float* __restrict__ W_fre,const float* __restrict__ U_fre,const float* __restrict__ b_fre,
    const float* __restrict__ W_c,  const float* __restrict__ U_c,  const float* __restrict__ b_c,
    const float* __restrict__ W_o,  const float* __restrict__ U_o,  const float* __restrict__ b_o,
    const float* __restrict__ U_a,  const float* __restrict__ b_a,
    const float* __restrict__ W_p,  const float* __restrict__ b_p,
    float* __restrict__ out)
{
    const int tid  = threadIdx.x;
    const int lane = tid & 63;
    const int wave = tid >> 6;      // 0..7
    const int q    = lane >> 4;     // quad 0..3
    const int n16  = lane & 15;
    const int b0   = blockIdx.x * NB;

    __shared__ __align__(16) unsigned short xsp[NB * XS];   // presplit x records
    __shared__ __align__(16) unsigned short hsp2[16 * HSK]; // rows 0-7 hhi(b), 8-15 hlo(b)
    __shared__ __align__(16) float zt[4 * 16 * ZC];         // [g][col(part,b)][hcol]
    __shared__ __align__(16) float fbp[3][16][16];          // fre raw partials [chunk][col][frow]
    __shared__ float red[8][8];

    // ---- init: stage + pre-split x (one (b,s) record per thread) ----
    if (tid < NB * TT) {
        const float* xg = x + (size_t)b0 * (TT * DD) + tid * DD;
        const int b = tid / TT, s = tid - b * TT;
        unsigned short* dst = &xsp[b * XS + s * 16];
        #pragma unroll
        for (int d = 0; d < DD; ++d) {
            const float v = xg[d];
            const unsigned short hb = f2bf(v);
            dst[d]     = hb;
            dst[8 + d] = f2bf(v - bf2f(hb));
        }
        dst[6] = 0x3F80; dst[7] = 0;   // k=70 bias row: 1.0 (hi), k=71: 0
        dst[14] = 0; dst[15] = 0;      // lo-part: k=70,71 = 0
    }
    for (int i = tid; i < 16 * HSK; i += 512) hsp2[i] = 0;   // h = 0 (hi & lo)

    // ---- gate A-frags (STATIC, U^T): wave w owns tiles gt=2w, 2w+1
    //      (g=gt>>2, mt=gt&3). A[m=n16][k=c*32+q*8+j];
    //      k: 0-63 U, 64-69 W, 70 bias. ----
    bf16x8 Ah[2][3], Al[2][3];
    #pragma unroll
    for (int t = 0; t < 2; ++t) {
        const int gt = 2 * wave + t;
        const int g  = gt >> 2, mt = gt & 3;
        const int col = mt * 16 + n16;
        const float* Ug = (g == 0) ? U_i : (g == 1) ? U_ste : (g == 2) ? U_c : U_o;
        const float* Wg = (g == 0) ? W_i : (g == 1) ? W_ste : (g == 2) ? W_c : W_o;
        const float* bg = (g == 0) ? b_i : (g == 1) ? b_ste : (g == 2) ? b_c : b_o;
        #pragma unroll
        for (int c = 0; c < 3; ++c) {
            #pragma unroll
            for (int j = 0; j < 8; ++j) {
                const int kv = c * 32 + q * 8 + j;
                float v = 0.0f;
                if      (kv < 64)  v = Ug[kv * HH + col];
                else if (kv < 70)  v = Wg[(kv - 64) * HH + col];
                else if (kv == 70) v = bg[col];
                const unsigned short hb = f2bf(v);
                Ah[t][c][j] = (short)hb;
                Al[t][c][j] = (short)f2bf(v - bf2f(hb));
            }
            pinv(Ah[t][c]); pinv(Al[t][c]);
        }
    }

    // ---- fre A-frag chunk: wave 5 -> c=0 (B0), wave 6 -> c=1 (B1),
    //      wave 7 -> c=2 (x, pre-issued) ----
    bf16x8 AhF = {0,0,0,0,0,0,0,0}, AlF = {0,0,0,0,0,0,0,0};
    if (wave >= 5) {
        const int c = wave - 5;
        #pragma unroll
        for (int j = 0; j < 8; ++j) {
            const int kv = c * 32 + q * 8 + j;
            float v = 0.0f;
            if (n16 < FF) {
                if      (kv < 64)  v = U_fre[kv * FF + n16];
                else if (kv < 70)  v = W_fre[(kv - 64) * FF + n16];
                else if (kv == 70) v = b_fre[n16];
            }
            const unsigned short hb = f2bf(v);
            AhF[j] = (short)hb;
            AlF[j] = (short)f2bf(v - bf2f(hb));
        }
        pinv(AhF); pinv(AlF);
    }

    // ---- pointwise consts: pb = tid&7, pc = tid>>3 (0..63) ----
    const int pb = tid & 7;
    const int pc = tid >> 3;
    const float bav = b_a[pc];
    const float wpv = W_p[pc];
    const float bpv = uni(b_p[0]);
    float uav[FF];
    #pragma unroll
    for (int f = 0; f < FF; ++f) uav[f] = uni(U_a[f]);

    // Rotated-phasor state (R15/R18-verified): T(f,t)=S*e^{-i*2pi*f*t/10};
    // T' = fc * R_f * T + cv, R_f const; A = |T|^2.
    const float CRT[10] = { 1.0f,  0.8090169943749475f,  0.30901699437494745f,
                           -0.30901699437494745f, -0.8090169943749475f, -1.0f,
                           -0.8090169943749475f, -0.30901699437494745f,
                            0.30901699437494745f,  0.8090169943749475f };
    const float SRT[10] = { 0.0f,  0.5877852522924731f,  0.9510565162951535f,
                            0.9510565162951535f,  0.5877852522924731f,  0.0f,
                           -0.5877852522924731f, -0.9510565162951535f,
                           -0.9510565162951535f, -0.5877852522924731f };

    float Tre[FF], Tim[FF];
    #pragma unroll
    for (int f = 0; f < FF; ++f) { Tre[f] = 0.0f; Tim[f] = 0.0f; }
    float hv = 0.0f;

    // B-frag addresses (dynamic h + x record)
    const unsigned short* hrp = &hsp2[n16 * HSK];
    const unsigned short* xrp = &xsp[(n16 & 7) * XS + (n16 >> 3) * 8];

    __syncthreads();

    // ---- pre-issue x-chunk MFMAs for s=0 ----
    const bf16x8 zf8 = {0, 0, 0, 0, 0, 0, 0, 0};
    f32x4 accPre[2];
    f32x4 accPreF = {0.0f, 0.0f, 0.0f, 0.0f};
    {
        const bf16x8 xv0 = *(const bf16x8*)&xrp[0];
        const bf16x8 B2 = (q == 0) ? xv0 : zf8;
        #pragma unroll
        for (int t = 0; t < 2; ++t) {
            f32x4 a = {0.0f, 0.0f, 0.0f, 0.0f};
            a = __builtin_amdgcn_mfma_f32_16x16x32_bf16(Ah[t][2], B2, a, 0, 0, 0);
            a = __builtin_amdgcn_mfma_f32_16x16x32_bf16(Al[t][2], B2, a, 0, 0, 0);
            accPre[t] = a;
        }
        if (wave == 7) {
            f32x4 a = {0.0f, 0.0f, 0.0f, 0.0f};
            a = __builtin_amdgcn_mfma_f32_16x16x32_bf16(AhF, B2, a, 0, 0, 0);
            a = __builtin_amdgcn_mfma_f32_16x16x32_bf16(AlF, B2, a, 0, 0, 0);
            accPreF = a;
        }
    }

    for (int s = 0; s < TT; ++s) {
        // ---- M: h chunks from LDS, gate chains start at accPre ----
        const bf16x8 B0 = *(const bf16x8*)&hrp[q * 8];
        const bf16x8 B1 = *(const bf16x8*)&hrp[32 + q * 8];

        #pragma unroll
        for (int t = 0; t < 2; ++t) {
            f32x4 a = accPre[t];
            a = __builtin_amdgcn_mfma_f32_16x16x32_bf16(Ah[t][0], B0, a, 0, 0, 0);
            a = __builtin_amdgcn_mfma_f32_16x16x32_bf16(Al[t][0], B0, a, 0, 0, 0);
            a = __builtin_amdgcn_mfma_f32_16x16x32_bf16(Ah[t][1], B1, a, 0, 0, 0);
            a = __builtin_amdgcn_mfma_f32_16x16x32_bf16(Al[t][1], B1, a, 0, 0, 0);
            const int gt = 2 * wave + t;
            const int g  = gt >> 2, mt = gt & 3;
            *(f32x4*)&zt[(g * 16 + n16) * ZC + mt * 16 + q * 4] = a;
        }
        // fre partials: raw, per-chunk; fold happens in P
        if (wave == 5) {
            f32x4 a = {0.0f, 0.0f, 0.0f, 0.0f};
            a = __builtin_amdgcn_mfma_f32_16x16x32_bf16(AhF, B0, a, 0, 0, 0);
            a = __builtin_amdgcn_mfma_f32_16x16x32_bf16(AlF, B0, a, 0, 0, 0);
            *(f32x4*)&fbp[0][n16][q * 4] = a;
        } else if (wave == 6) {
            f32x4 a = {0.0f, 0.0f, 0.0f, 0.0f};
            a = __builtin_amdgcn_mfma_f32_16x16x32_bf16(AhF, B1, a, 0, 0, 0);
            a = __builtin_amdgcn_mfma_f32_16x16x32_bf16(AlF, B1, a, 0, 0, 0);
            *(f32x4*)&fbp[1][n16][q * 4] = a;
        } else if (wave == 7) {
            *(f32x4*)&fbp[2][n16][q * 4] = accPreF;   // x-chunk, pre-issued
        }
        __syncthreads();

        // ---- P: batch pb, col pc ----
        const int sn = (s + 1 < TT) ? s + 1 : 0;
        const bf16x8 xvN = *(const bf16x8*)&xrp[sn * 16];   // prefetch next x

        // z = hi-col + lo-col (full product); zc first (longest chain)
        const float zcH = zt[(2 * 16 + pb) * ZC + pc], zcL = zt[(2 * 16 + pb + 8) * ZC + pc];
        const float ziH = zt[(0 * 16 + pb) * ZC + pc], ziL = zt[(0 * 16 + pb + 8) * ZC + pc];
        const float zsH = zt[(1 * 16 + pb) * ZC + pc], zsL = zt[(1 * 16 + pb + 8) * ZC + pc];
        const float zoH = zt[(3 * 16 + pb) * ZC + pc], zoL = zt[(3 * 16 + pb + 8) * ZC + pc];

        // fre: sum 3 chunk-partials x (hi col pb, lo col pb+8)
        f32x4 sA = *(const f32x4*)&fbp[0][pb][0];
        sA = sA + *(const f32x4*)&fbp[0][pb + 8][0];
        sA = sA + *(const f32x4*)&fbp[1][pb][0];
        sA = sA + *(const f32x4*)&fbp[1][pb + 8][0];
        sA = sA + *(const f32x4*)&fbp[2][pb][0];
        sA = sA + *(const f32x4*)&fbp[2][pb + 8][0];
        f32x4 sB = *(const f32x4*)&fbp[0][pb][4];
        sB = sB + *(const f32x4*)&fbp[0][pb + 8][4];
        sB = sB + *(const f32x4*)&fbp[1][pb][4];
        sB = sB + *(const f32x4*)&fbp[1][pb + 8][4];
        sB = sB + *(const f32x4*)&fbp[2][pb][4];
        sB = sB + *(const f32x4*)&fbp[2][pb + 8][4];
        f32x2 sC = *(const f32x2*)&fbp[0][pb][8];
        sC = sC + *(const f32x2*)&fbp[0][pb + 8][8];
        sC = sC + *(const f32x2*)&fbp[1][pb][8];
        sC = sC + *(const f32x2*)&fbp[1][pb + 8][8];
        sC = sC + *(const f32x2*)&fbp[2][pb][8];
        sC = sC + *(const f32x2*)&fbp[2][pb + 8][8];

        float fr[FF];
        fr[0] = hsig_f(sA[0]); fr[1] = hsig_f(sA[1]);
        fr[2] = hsig_f(sA[2]); fr[3] = hsig_f(sA[3]);
        fr[4] = hsig_f(sB[0]); fr[5] = hsig_f(sB[1]);
        fr[6] = hsig_f(sB[2]); fr[7] = hsig_f(sB[3]);
        fr[8] = hsig_f(sC[0]); fr[9] = hsig_f(sC[1]);

        const float cvt = tanh_f(zcH + zcL);
        const float iv  = hsig_f(ziH + ziL);
        const float stv = hsig_f(zsH + zsL);
        const float ov  = hsig_f(zoH + zoL);
        const float cv  = iv * cvt;

        float aacc0 = bav, aacc1 = 0.0f;
        #pragma unroll
        for (int f = 0; f < FF; ++f) {
            const float fc = stv * fr[f];
            // T' = fc * (R_f * T) + cv,  R_f = cos - i sin
            const float tre = fmaf(SRT[f], Tim[f],  CRT[f] * Tre[f]);
            const float tim = fmaf(CRT[f], Tim[f], -SRT[f] * Tre[f]);
            Tre[f] = fmaf(fc, tre, cv);
            Tim[f] = fc * tim;
            const float A = fmaf(Tim[f], Tim[f], Tre[f] * Tre[f]);
            if (f & 1) aacc1 = fmaf(A, uav[f], aacc1);
            else       aacc0 = fmaf(A, uav[f], aacc0);
        }
        hv = ov * tanh_f(aacc0 + aacc1);

        // split h -> bf16 hi/lo rows (the ONLY conversion point)
        {
            const unsigned short hb = f2bf(hv);
            hsp2[pb * HSK + pc]       = hb;
            hsp2[(8 + pb) * HSK + pc] = f2bf(hv - bf2f(hb));
        }

        // ---- pre-issue x-chunk MFMAs for s+1 (matrix pipe idle in P) ----
        {
            const bf16x8 B2 = (q == 0) ? xvN : zf8;
            #pragma unroll
            for (int t = 0; t < 2; ++t) {
                f32x4 a = {0.0f, 0.0f, 0.0f, 0.0f};
                a = __builtin_amdgcn_mfma_f32_16x16x32_bf16(Ah[t][2], B2, a, 0, 0, 0);
                a = __builtin_amdgcn_mfma_f32_16x16x32_bf16(Al[t][2], B2, a, 0, 0, 0);
                accPre[t] = a;
            }
            if (wave == 7) {
                f32x4 a = {0.0f, 0.0f, 0.0f, 0.0f};
                a = __builtin_amdgcn_mfma_f32_16x16x32_bf16(AhF, B2, a, 0, 0, 0);
                a = __builtin_amdgcn_mfma_f32_16x16x32_bf16(AlF, B2, a, 0, 0, 0);
                accPreF = a;
                pinvf(accPreF);
            }
            pinvf(accPre[0]); pinvf(accPre[1]);   // keep issue pre-barrier
        }
        __syncthreads();
    }

    // ---- output: out[b] = sum_col h*W_p + b_p ----
    // lane bits: pb = lane&7, pc-octet bits = lane>>3 -> fold lanes 8,16,32
    float val = hv * wpv;
    val += __shfl_xor(val, 8, 64);
    val += __shfl_xor(val, 16, 64);
    val += __shfl_xor(val, 32, 64);
    if (lane < 8) red[wave][lane] = val;
    __syncthreads();
    if (tid < NB) {
        float acc = bpv;
        #pragma unroll
        for (int w = 0; w < 8; ++w) acc += red[w][tid];
        out[b0 + tid] = acc;
    }
}

extern "C" void kernel_launch(void* const* d_in, const int* in_sizes, int n_in,
                              void* d_out, int out_size, void* d_ws, size_t ws_size,
                              hipStream_t stream) {
    (void)in_sizes; (void)n_in; (void)d_ws; (void)ws_size; (void)out_size;
    const float* x     = (const float*)d_in[0];
    const float* W_i   = (const float*)d_in[1];
    const float* U_i   = (const float*)d_in[2];
    const float* b_i   = (const float*)d_in[3];
    const float* W_ste = (const float*)d_in[4];
    const float* U_ste = (const float*)d_in[5];
    const float* b_ste = (const float*)d_in[6];
    const float* W_fre = (const float*)d_in[7];
    const float* U_fre = (const float*)d_in[8];
    const float* b_fre = (const float*)d_in[9];
    const float* W_c   = (const float*)d_in[10];
    const float* U_c   = (const float*)d_in[11];
    const float* b_c   = (const float*)d_in[12];
    const float* W_o   = (const float*)d_in[13];
    const float* U_o   = (const float*)d_in[14];
    const float* b_o   = (const float*)d_in[15];
    const float* U_a   = (const float*)d_in[16];
    const float* b_a   = (const float*)d_in[17];
    const float* W_p   = (const float*)d_in[18];
    const float* b_p   = (const float*)d_in[19];

    sfm_kernel<<<BB / NB, 512, 0, stream>>>(
        x, W_i, U_i, b_i, W_ste, U_ste, b_ste, W_fre, U_fre, b_fre,
        W_c, U_c, b_c, W_o, U_o, b_o, U_a, b_a, W_p, b_p, (float*)d_out);
}